// Round 4
// baseline (221.735 us; speedup 1.0000x reference)
//
#include <hip/hip_runtime.h>

typedef _Float16 half8 __attribute__((ext_vector_type(8)));
typedef _Float16 half4v __attribute__((ext_vector_type(4)));
typedef float floatx4 __attribute__((ext_vector_type(4)));

// ---------------------------------------------------------------------------
// Decoder: 6 conv_transpose3d (JAX SAME, no kernel flip), fp16 MFMA.
// R4: pads fused into conv A-staging (read prev fp32 out + bounds + ReLU +
// cvt), stride-2 layers balanced via 27 (class,tap) pairs in blockIdx.x,
// s1 layers split into tap-groups for occupancy, M=128xN=64 wave tiles.
// 8 dispatches total: memset, pad_x, conv1..conv5, conv6.
// ---------------------------------------------------------------------------

__global__ __launch_bounds__(256) void pad_x_k(const float* __restrict__ X,
                                               _Float16* __restrict__ P) {
  int idx = blockIdx.x * 256 + threadIdx.x;   // P1: [5][5][5][1024]
  if (idx >= 125 * 1024) return;
  int c = idx & 1023;
  int r = idx >> 10;
  int px = r % 5, py = (r / 5) % 5, pz = r / 25;
  float v = 0.f;
  if (px >= 1 && py >= 1 && pz >= 1)
    v = X[c * 64 + (pz - 1) * 16 + (py - 1) * 4 + (px - 1)];  // NCDHW -> cl
  P[idx] = (_Float16)v;
}

__device__ __forceinline__ half8 cvt_relu8(const float4& f0, const float4& f1) {
  half8 h;
  h[0] = (_Float16)fmaxf(f0.x, 0.f);
  h[1] = (_Float16)fmaxf(f0.y, 0.f);
  h[2] = (_Float16)fmaxf(f0.z, 0.f);
  h[3] = (_Float16)fmaxf(f0.w, 0.f);
  h[4] = (_Float16)fmaxf(f1.x, 0.f);
  h[5] = (_Float16)fmaxf(f1.y, 0.f);
  h[6] = (_Float16)fmaxf(f1.z, 0.f);
  h[7] = (_Float16)fmaxf(f1.w, 0.f);
  return h;
}

// SMODE: 0 = stride1 (tap-groups of TAPG via blockIdx.z), 1 = stride2 with
// (class,tap) pairs in blockIdx.x, 2 = stride2 class-loop (L5).
// IN_MODE: 0 = fp16 left-padded P (L1), 1 = fp32 prev output + bounds + ReLU.
// STORE_MODE: 1 = fp32 atomicAdd, 2 = fp16 ReLU store into padded (S+2)^3.
template <int CICHUNK, int CIN, int COUT, int NTILE, int TZ, int SOUTU,
          int SMODE, int TAPG, int IN_MODE, int STORE_MODE>
__global__ __launch_bounds__(256) void conv_mfma_k(
    const void* __restrict__ Pin, const float* __restrict__ W,
    void* __restrict__ Optr) {
  constexpr int M = TZ * 16;               // 64 or 128
  constexpr bool S2 = (SMODE != 0);
  constexpr int MTZ = SOUTU / TZ;
  constexpr int MTXY = SOUTU / 4;
  constexpr int MT3 = MTZ * MTXY * MTXY;
  constexpr int KB = 32;
  constexpr int KP = 40;
  constexpr int KBI = CICHUNK / KB;
  constexpr int NCI = CIN / CICHUNK;
  constexpr int S = S2 ? 2 * SOUTU : SOUTU;
  constexpr int WM = (M == 128) ? 4 : 2;   // waves along m
  constexpr int NSUB = (WM == 4) ? (NTILE / 16) : (NTILE / 32);
  constexpr int BJ = KB * NTILE / 256;     // B fp32 loads per thread

  __shared__ __align__(16) _Float16 As[M][KP];
  __shared__ __align__(16) _Float16 Bs[NTILE][KP];

  int bx = blockIdx.x;
  int cls = 0, tap0 = 0, cig = blockIdx.z;
  int p_toz = 0, p_toy = 0, p_tox = 0, p_wtap = 0;  // SMODE==1 block consts
  if (SMODE == 0) {
    const int tg = cig / NCI;              // blockIdx.z = tg*NCI + cig
    cig -= tg * NCI;
    tap0 = tg * TAPG;
  } else if (SMODE == 1) {
    const int p = bx / MT3;
    bx -= p * MT3;
    cls = (p >= 8) + (p >= 12) + (p >= 16) + (p >= 18) + (p >= 22) +
          (p >= 24) + (p >= 26);
    const int pf = cls == 0 ? 0 : cls == 1 ? 8 : cls == 2 ? 12
                 : cls == 3 ? 16 : cls == 4 ? 18 : cls == 5 ? 22
                 : cls == 6 ? 24 : 26;
    const int tl = p - pf;
    const int lz = (cls >> 2) & 1, ly = (cls >> 1) & 1, lx = cls & 1;
    const int shx = lx ? 0 : 1, shy = ly ? 0 : 1;
    const int iz = tl >> (shx + shy);
    const int rem = tl & ((1 << (shx + shy)) - 1);
    const int iy = rem >> shx;
    const int ix = rem & ((1 << shx) - 1);
    p_toz = lz ? 1 : iz;
    p_toy = ly ? 1 : iy;
    p_tox = lx ? 1 : ix;
    const int wz = lz ? 1 : 2 * iz, wy = ly ? 1 : 2 * iy,
              wx = lx ? 1 : 2 * ix;
    p_wtap = (wz * 3 + wy) * 3 + wx;
  } else {
    cls = bx / MT3;
    bx -= cls * MT3;
  }
  const int clz = (cls >> 2) & 1, cly = (cls >> 1) & 1, clx = cls & 1;

  const int u0z = (bx / (MTXY * MTXY)) * TZ;
  const int u0y = ((bx / MTXY) % MTXY) * 4;
  const int u0x = (bx % MTXY) * 4;
  const int n_base = blockIdx.y * NTILE;

  const int t = threadIdx.x;
  const int lane = t & 63;
  const int wave = t >> 6;

  // A staging: thread t -> position sp (z-major 4x4x4), k-chunk skq
  const int skq = t & 3;
  const int sp = t >> 2;
  const int spx = sp & 3, spy = (sp >> 2) & 3, spz = sp >> 4;
  // B staging: thread t -> n-row nB, k range [k0B, k0B+BJ)
  const int nB = t & (NTILE - 1);
  const int k0B = (t / NTILE) * BJ;
  // compute mapping
  const int m0w = (WM == 4) ? wave * 32 : (wave >> 1) * 32;
  const int n0w = (WM == 4) ? 0 : (wave & 1) * 32;
  const int fr = lane & 15;
  const int fq = lane >> 4;

  const int cz = S2 ? (clz ? 1 : 2) : 3;
  const int cy = S2 ? (cly ? 1 : 2) : 3;
  const int cx = S2 ? (clx ? 1 : 2) : 3;
  const int shx2 = clx ? 0 : 1, shy2 = cly ? 0 : 1;

  int NIT;
  if (SMODE == 0) NIT = TAPG * KBI;
  else if (SMODE == 1) NIT = KBI;
  else NIT = cz * cy * cx * KBI;

  floatx4 acc[2][NSUB];
#pragma unroll
  for (int i = 0; i < 2; i++)
#pragma unroll
    for (int s = 0; s < NSUB; s++) acc[i][s] = {0.f, 0.f, 0.f, 0.f};

  half8 rA0 = {}, rA1 = {}, nA0 = {}, nA1 = {};
  float rB[BJ] = {}, nBv[BJ] = {};

  auto load_it = [&](int it, half8& A0, half8& A1, float* BW) {
    int tap, kb;
    if (SMODE == 1) { tap = 0; kb = it; }
    else if (KBI == 1) { tap = it; kb = 0; }
    else { tap = it / KBI; kb = it - tap * KBI; }
    int toz, toy, tox, wtap;
    if (SMODE == 1) {
      toz = p_toz; toy = p_toy; tox = p_tox; wtap = p_wtap;
    } else if (SMODE == 0) {
      const int tt = tap0 + tap;
      const int iz = tt / 9;
      const int rem = tt - iz * 9;
      const int iy = rem / 3;
      const int ix = rem - iy * 3;
      toz = iz; toy = iy; tox = ix;
      wtap = tt;
    } else {
      const int iz = tap >> (shx2 + shy2);
      const int rem = tap & ((1 << (shx2 + shy2)) - 1);
      const int iy = rem >> shx2;
      const int ix = rem & ((1 << shx2) - 1);
      toz = clz ? 1 : iz; toy = cly ? 1 : iy; tox = clx ? 1 : ix;
      const int wz = clz ? 1 : 2 * iz, wy = cly ? 1 : 2 * iy,
                wx = clx ? 1 : 2 * ix;
      wtap = (wz * 3 + wy) * 3 + wx;
    }
    const int kof0 = cig * CICHUNK + kb * KB;
    if (IN_MODE == 0) {
      constexpr int PS = SOUTU + 1;        // left-pad-1 fp16 buffer
      const _Float16* Pp = (const _Float16*)Pin;
      const size_t pb =
          ((size_t)(((u0z + toz + spz) * PS + (u0y + toy + spy)) * PS +
                    (u0x + tox + spx))) * CIN + kof0 + skq * 8;
      A0 = *(const half8*)(Pp + pb);
      if (M == 128)
        A1 = *(const half8*)(Pp + pb + (size_t)4 * PS * PS * CIN);
    } else {
      const float* Ip = (const float*)Pin;
      const int izc = u0z + toz + spz - 1;
      const int iyc = u0y + toy + spy - 1;
      const int ixc = u0x + tox + spx - 1;
      const bool okyx = ((unsigned)iyc < (unsigned)SOUTU) &
                        ((unsigned)ixc < (unsigned)SOUTU);
      const float* src =
          Ip + ((size_t)((izc * SOUTU + iyc) * SOUTU + ixc)) * CIN + kof0 +
          skq * 8;
      float4 f0 = make_float4(0.f, 0.f, 0.f, 0.f);
      float4 f1 = make_float4(0.f, 0.f, 0.f, 0.f);
      if (okyx && ((unsigned)izc < (unsigned)SOUTU)) {
        f0 = *(const float4*)src;
        f1 = *(const float4*)(src + 4);
      }
      A0 = cvt_relu8(f0, f1);
      if (M == 128) {
        float4 g0 = make_float4(0.f, 0.f, 0.f, 0.f);
        float4 g1 = make_float4(0.f, 0.f, 0.f, 0.f);
        if (okyx && ((unsigned)(izc + 4) < (unsigned)SOUTU)) {
          const float* s2p = src + (size_t)4 * SOUTU * SOUTU * CIN;
          g0 = *(const float4*)s2p;
          g1 = *(const float4*)(s2p + 4);
        }
        A1 = cvt_relu8(g0, g1);
      }
    }
    const float* wb =
        W + ((size_t)wtap * CIN + kof0 + k0B) * COUT + n_base + nB;
#pragma unroll
    for (int j = 0; j < BJ; j++) BW[j] = wb[(size_t)j * COUT];
  };

  load_it(0, rA0, rA1, rB);

  for (int it = 0; it < NIT; ++it) {
    *(half8*)&As[sp][skq * 8] = rA0;
    if (M == 128) *(half8*)&As[sp + 64][skq * 8] = rA1;
    if (BJ == 8) {
      half8 hb;
#pragma unroll
      for (int j = 0; j < 8; j++) hb[j] = (_Float16)rB[j];
      *(half8*)&Bs[nB][k0B] = hb;
    } else {
      half4v hb;
#pragma unroll
      for (int j = 0; j < 4; j++) hb[j] = (_Float16)rB[j];
      *(half4v*)&Bs[nB][k0B] = hb;
    }
    __syncthreads();
    if (it + 1 < NIT) load_it(it + 1, nA0, nA1, nBv);
    half8 a0 = *(const half8*)&As[m0w + fr][fq * 8];
    half8 a1 = *(const half8*)&As[m0w + 16 + fr][fq * 8];
#pragma unroll
    for (int s = 0; s < NSUB; s++) {
      half8 b = *(const half8*)&Bs[n0w + s * 16 + fr][fq * 8];
      acc[0][s] = __builtin_amdgcn_mfma_f32_16x16x32_f16(a0, b, acc[0][s], 0, 0, 0);
      acc[1][s] = __builtin_amdgcn_mfma_f32_16x16x32_f16(a1, b, acc[1][s], 0, 0, 0);
    }
    __syncthreads();
    rA0 = nA0;
    rA1 = nA1;
#pragma unroll
    for (int j = 0; j < BJ; j++) rB[j] = nBv[j];
  }

#pragma unroll
  for (int i = 0; i < 2; i++) {
#pragma unroll
    for (int r = 0; r < 4; r++) {
      const int m = m0w + i * 16 + fq * 4 + r;
      const int mz = m >> 4, my = (m >> 2) & 3, mx = m & 3;
      int oz, oy, ox;
      if (S2) {
        oz = 2 * (u0z + mz) + clz;
        oy = 2 * (u0y + my) + cly;
        ox = 2 * (u0x + mx) + clx;
      } else {
        oz = u0z + mz;
        oy = u0y + my;
        ox = u0x + mx;
      }
      if (STORE_MODE == 2) {
        _Float16* o = (_Float16*)Optr +
            ((size_t)(((oz + 1) * (S + 2) + (oy + 1)) * (S + 2) + (ox + 1))) *
                COUT + n_base + n0w;
#pragma unroll
        for (int s = 0; s < NSUB; s++)
          o[s * 16 + fr] = (_Float16)fmaxf(acc[i][s][r], 0.f);
      } else {
        float* o = (float*)Optr +
            ((size_t)((oz * S + oy) * S + ox)) * COUT + n_base + n0w;
#pragma unroll
        for (int s = 0; s < NSUB; s++) atomicAdd(o + s * 16 + fr, acc[i][s][r]);
      }
    }
  }
}

// Layer 6: 32 -> 1 channels, per-output dot product from padded fp16 P6.
__global__ __launch_bounds__(256) void conv6_k(const _Float16* __restrict__ P,
                                               const float* __restrict__ W6,
                                               float* __restrict__ O) {
  __shared__ __align__(16) float w[864];  // 27*32
  for (int i = threadIdx.x; i < 864; i += 256) w[i] = W6[i];
  __syncthreads();
  int idx = blockIdx.x * 256 + threadIdx.x;  // 32768 outputs
  int x = idx & 31, y = (idx >> 5) & 31, z = idx >> 10;
  float a = 0.f;
  for (int dz = 0; dz < 3; dz++)
    for (int dy = 0; dy < 3; dy++)
      for (int dx = 0; dx < 3; dx++) {
        const _Float16* p =
            P + (size_t)(((z + dz) * 34 + (y + dy)) * 34 + (x + dx)) * 32;
        const float* ww = &w[((dz * 3 + dy) * 3 + dx) * 32];
#pragma unroll
        for (int c = 0; c < 32; c += 8) {
          half8 pv = *(const half8*)&p[c];
#pragma unroll
          for (int u = 0; u < 8; u++) a += (float)pv[u] * ww[c + u];
        }
      }
  O[idx] = a;
}

extern "C" void kernel_launch(void* const* d_in, const int* in_sizes, int n_in,
                              void* d_out, int out_size, void* d_ws,
                              size_t ws_size, hipStream_t stream) {
  const float* x  = (const float*)d_in[0];
  const float* w1 = (const float*)d_in[1];
  const float* w2 = (const float*)d_in[2];
  const float* w3 = (const float*)d_in[3];
  const float* w4 = (const float*)d_in[4];
  const float* w5 = (const float*)d_in[5];
  const float* w6 = (const float*)d_in[6];
  float* out = (float*)d_out;

  // ws layout: fp32 atomic outs O1..O4, then fp16 P6 (all zeroed), then P1.
  float* O1 = (float*)d_ws;                  // 8^3 *512  = 262144
  float* O2 = O1 + 262144;                   // 8^3 *256  = 131072
  float* O3 = O2 + 131072;                   // 16^3*128  = 524288
  float* O4 = O3 + 524288;                   // 16^3*64   = 262144
  _Float16* P6 = (_Float16*)(O4 + 262144);   // 34^3*32   = 1257728
  _Float16* P1 = P6 + 1257728;               // 5^3 *1024 = 128000

  hipMemsetAsync(d_ws, 0,
                 1179648 * sizeof(float) + 1257728 * sizeof(_Float16), stream);

  // L1: 1024->512, 4^3 -> 8^3, s2, pairs; 27x8x4 = 864 blocks, NIT=8
  pad_x_k<<<500, 256, 0, stream>>>(x, P1);
  conv_mfma_k<256, 1024, 512, 64, 4, 4, 1, 0, 0, 1>
      <<<dim3(27, 8, 4), 256, 0, stream>>>(P1, w1, O1);
  // L2: 512->256, 8^3, s1, tap-groups; 4x4x24 = 384 blocks, NIT=18
  conv_mfma_k<64, 512, 256, 64, 8, 8, 0, 9, 1, 1>
      <<<dim3(4, 4, 24), 256, 0, stream>>>(O1, w2, O2);
  // L3: 256->128, 8^3 -> 16^3, s2 pairs; 108x2x2 = 432 blocks, NIT=4
  conv_mfma_k<128, 256, 128, 64, 8, 8, 1, 0, 1, 1>
      <<<dim3(108, 2, 2), 256, 0, stream>>>(O2, w3, O3);
  // L4: 128->64, 16^3, s1 tap-groups; 32x1x12 = 384 blocks, NIT=9
  conv_mfma_k<32, 128, 64, 64, 8, 16, 0, 9, 1, 1>
      <<<dim3(32, 1, 12), 256, 0, stream>>>(O3, w4, O4);
  // L5: 64->32, 16^3 -> 32^3, s2 class-loop, fp16 ReLU store into padded P6
  conv_mfma_k<64, 64, 32, 32, 8, 16, 2, 0, 1, 2>
      <<<dim3(256, 1, 1), 256, 0, stream>>>(O4, w5, P6);
  // L6: 32->1, 32^3, s1, no final ReLU
  conv6_k<<<128, 256, 0, stream>>>(P6, w6, out);

  (void)in_sizes; (void)n_in; (void)out_size; (void)ws_size;
}

// Round 5
// 208.461 us; speedup vs baseline: 1.0637x; 1.0637x over previous
//
#include <hip/hip_runtime.h>

typedef _Float16 half8 __attribute__((ext_vector_type(8)));
typedef _Float16 half4v __attribute__((ext_vector_type(4)));
typedef float floatx4 __attribute__((ext_vector_type(4)));

// ---------------------------------------------------------------------------
// Decoder: 6 conv_transpose3d (JAX SAME, no kernel flip), fp16 MFMA.
// R5: NO ATOMICS. Convs write disjoint fp32 partial slabs (split = tap-group/
// pair x ci-chunk); a fused reduce kernel per layer sums splits + ReLU + cvt
// fp16 + writes the padded channels-last input of the next layer (borders
// included). Stride-2 layers use balanced 27 (class,tap) pairs; class pairs
// are contiguous so the reduce's split range is [pf(c)*NCI,(pf(c)+T(c))*NCI).
// ---------------------------------------------------------------------------

__global__ __launch_bounds__(256) void pad_x_k(const float* __restrict__ X,
                                               _Float16* __restrict__ P) {
  int idx = blockIdx.x * 256 + threadIdx.x;   // P1: [5][5][5][1024]
  if (idx >= 125 * 1024) return;
  int c = idx & 1023;
  int r = idx >> 10;
  int px = r % 5, py = (r / 5) % 5, pz = r / 25;
  float v = 0.f;
  if (px >= 1 && py >= 1 && pz >= 1)
    v = X[c * 64 + (pz - 1) * 16 + (py - 1) * 4 + (px - 1)];  // NCDHW -> cl
  P[idx] = (_Float16)v;
}

// Reduce partials -> ReLU -> fp16 -> padded next-layer input (borders = 0).
// POS = producer spatial size, S2IN = producer was stride-2 (class-variable
// split count), NSPL = ci-splits (s2) or total splits (s1), PS = padded size.
template <int POS, int COUT, int S2IN, int NSPL, int PS>
__global__ __launch_bounds__(256) void red_k(const float* __restrict__ Pp,
                                             _Float16* __restrict__ P) {
  constexpr int C4 = COUT / 4;
  constexpr size_t U3 =
      S2IN ? (size_t)(POS / 2) * (POS / 2) * (POS / 2) : (size_t)POS * POS * POS;
  int idx = blockIdx.x * 256 + threadIdx.x;
  if (idx >= PS * PS * PS * C4) return;
  const int co = (idx % C4) * 4;
  const int r = idx / C4;
  const int px = r % PS, py = (r / PS) % PS, pz = r / (PS * PS);
  const int ix = px - 1, iy = py - 1, iz = pz - 1;
  float4 s = make_float4(0.f, 0.f, 0.f, 0.f);
  if ((unsigned)ix < (unsigned)POS && (unsigned)iy < (unsigned)POS &&
      (unsigned)iz < (unsigned)POS) {
    int j0, j1;
    size_t upos;
    if (S2IN) {
      const int pf[8] = {0, 8, 12, 16, 18, 22, 24, 26};
      const int tc[8] = {8, 4, 4, 2, 4, 2, 2, 1};
      const int cls = ((iz & 1) << 2) | ((iy & 1) << 1) | (ix & 1);
      j0 = pf[cls] * NSPL;
      j1 = j0 + tc[cls] * NSPL;
      constexpr int U = POS / 2;
      upos = ((size_t)(iz >> 1) * U + (iy >> 1)) * U + (ix >> 1);
    } else {
      j0 = 0;
      j1 = NSPL;
      upos = ((size_t)iz * POS + iy) * POS + ix;
    }
    const float* base = Pp + upos * COUT + co;
    for (int j = j0; j < j1; j++) {
      float4 v = *(const float4*)(base + (size_t)j * U3 * COUT);
      s.x += v.x; s.y += v.y; s.z += v.z; s.w += v.w;
    }
  }
  half4v h;
  h[0] = (_Float16)fmaxf(s.x, 0.f);
  h[1] = (_Float16)fmaxf(s.y, 0.f);
  h[2] = (_Float16)fmaxf(s.z, 0.f);
  h[3] = (_Float16)fmaxf(s.w, 0.f);
  *(half4v*)(P + (size_t)idx * 4) = h;
}

// MFMA implicit-GEMM conv. Block = 256 threads = 4 waves. Input: fp16 padded
// channels-last, PS per dim (left-pad 1; s1 layers additionally have right
// pad). SMODE: 0 = stride1 tap-groups, 1 = stride2 (class,tap) pairs in
// blockIdx.x, 2 = stride2 class-loop. STORE_MODE: 2 = fp16 ReLU store into
// padded (S+2)^3 buffer, 3 = fp32 partial slab store (no atomics).
template <int CICHUNK, int CIN, int COUT, int NTILE, int TZ, int SOUTU,
          int PS, int SMODE, int TAPG, int STORE_MODE>
__global__ __launch_bounds__(256) void conv_mfma_k(
    const _Float16* __restrict__ P, const float* __restrict__ W,
    void* __restrict__ Optr) {
  constexpr int M = TZ * 16;               // 64 or 128
  constexpr bool S2 = (SMODE != 0);
  constexpr int MTZ = SOUTU / TZ;
  constexpr int MTXY = SOUTU / 4;
  constexpr int MT3 = MTZ * MTXY * MTXY;
  constexpr int KB = 32;
  constexpr int KP = 40;
  constexpr int KBI = CICHUNK / KB;
  constexpr int NCI = CIN / CICHUNK;
  constexpr int S = S2 ? 2 * SOUTU : SOUTU;
  constexpr int WM = (M == 128) ? 4 : 2;   // waves along m
  constexpr int NSUB = (WM == 4) ? (NTILE / 16) : (NTILE / 32);
  constexpr int BJ = KB * NTILE / 256;     // B fp32 loads per thread
  constexpr size_t U3 = (size_t)SOUTU * SOUTU * SOUTU;

  __shared__ __align__(16) _Float16 As[M][KP];
  __shared__ __align__(16) _Float16 Bs[NTILE][KP];

  int bx = blockIdx.x;
  int cls = 0, tap0 = 0, cig = blockIdx.z, jspl = 0;
  int p_toz = 0, p_toy = 0, p_tox = 0, p_wtap = 0;
  if (SMODE == 0) {
    const int tg = cig / NCI;
    cig -= tg * NCI;
    tap0 = tg * TAPG;
    jspl = blockIdx.z;                     // tg*NCI + cig
  } else if (SMODE == 1) {
    const int p = bx / MT3;
    bx -= p * MT3;
    jspl = p * NCI + cig;
    cls = (p >= 8) + (p >= 12) + (p >= 16) + (p >= 18) + (p >= 22) +
          (p >= 24) + (p >= 26);
    const int pf = cls == 0 ? 0 : cls == 1 ? 8 : cls == 2 ? 12
                 : cls == 3 ? 16 : cls == 4 ? 18 : cls == 5 ? 22
                 : cls == 6 ? 24 : 26;
    const int tl = p - pf;
    const int lz = (cls >> 2) & 1, ly = (cls >> 1) & 1, lx = cls & 1;
    const int shx = lx ? 0 : 1, shy = ly ? 0 : 1;
    const int iz = tl >> (shx + shy);
    const int rem = tl & ((1 << (shx + shy)) - 1);
    const int iy = rem >> shx;
    const int ix = rem & ((1 << shx) - 1);
    p_toz = lz ? 1 : iz;
    p_toy = ly ? 1 : iy;
    p_tox = lx ? 1 : ix;
    const int wz = lz ? 1 : 2 * iz, wy = ly ? 1 : 2 * iy,
              wx = lx ? 1 : 2 * ix;
    p_wtap = (wz * 3 + wy) * 3 + wx;
  } else {
    cls = bx / MT3;
    bx -= cls * MT3;
  }
  const int clz = (cls >> 2) & 1, cly = (cls >> 1) & 1, clx = cls & 1;

  const int u0z = (bx / (MTXY * MTXY)) * TZ;
  const int u0y = ((bx / MTXY) % MTXY) * 4;
  const int u0x = (bx % MTXY) * 4;
  const int n_base = blockIdx.y * NTILE;

  const int t = threadIdx.x;
  const int lane = t & 63;
  const int wave = t >> 6;

  // A staging: thread t -> position sp (4x4x4 z-major), k-chunk skq
  const int skq = t & 3;
  const int sp = t >> 2;
  const int spx = sp & 3, spy = (sp >> 2) & 3, spz = sp >> 4;
  // B staging: thread t -> n-row nB, k range [k0B, k0B+BJ)
  const int nB = t & (NTILE - 1);
  const int k0B = (t / NTILE) * BJ;
  // compute mapping
  const int m0w = (WM == 4) ? wave * 32 : (wave >> 1) * 32;
  const int n0w = (WM == 4) ? 0 : (wave & 1) * 32;
  const int fr = lane & 15;
  const int fq = lane >> 4;

  const int cz = S2 ? (clz ? 1 : 2) : 3;
  const int cy = S2 ? (cly ? 1 : 2) : 3;
  const int cx = S2 ? (clx ? 1 : 2) : 3;
  const int shx2 = clx ? 0 : 1, shy2 = cly ? 0 : 1;

  int NIT;
  if (SMODE == 0) NIT = TAPG * KBI;
  else if (SMODE == 1) NIT = KBI;
  else NIT = cz * cy * cx * KBI;

  floatx4 acc[2][NSUB];
#pragma unroll
  for (int i = 0; i < 2; i++)
#pragma unroll
    for (int s = 0; s < NSUB; s++) acc[i][s] = {0.f, 0.f, 0.f, 0.f};

  half8 rA0 = {}, rA1 = {}, nA0 = {}, nA1 = {};
  float rB[BJ] = {}, nBv[BJ] = {};

  auto load_it = [&](int it, half8& A0, half8& A1, float* BW) {
    int tap, kb;
    if (SMODE == 1) { tap = 0; kb = it; }
    else if (KBI == 1) { tap = it; kb = 0; }
    else { tap = it / KBI; kb = it - tap * KBI; }
    int toz, toy, tox, wtap;
    if (SMODE == 1) {
      toz = p_toz; toy = p_toy; tox = p_tox; wtap = p_wtap;
    } else if (SMODE == 0) {
      const int tt = tap0 + tap;
      const int iz = tt / 9;
      const int rem = tt - iz * 9;
      const int iy = rem / 3;
      const int ix = rem - iy * 3;
      toz = iz; toy = iy; tox = ix;
      wtap = tt;
    } else {
      const int iz = tap >> (shx2 + shy2);
      const int rem = tap & ((1 << (shx2 + shy2)) - 1);
      const int iy = rem >> shx2;
      const int ix = rem & ((1 << shx2) - 1);
      toz = clz ? 1 : iz; toy = cly ? 1 : iy; tox = clx ? 1 : ix;
      const int wz = clz ? 1 : 2 * iz, wy = cly ? 1 : 2 * iy,
                wx = clx ? 1 : 2 * ix;
      wtap = (wz * 3 + wy) * 3 + wx;
    }
    const int kof0 = cig * CICHUNK + kb * KB;
    const size_t pb =
        ((size_t)(((u0z + toz + spz) * PS + (u0y + toy + spy)) * PS +
                  (u0x + tox + spx))) * CIN + kof0 + skq * 8;
    A0 = *(const half8*)(P + pb);
    if (M == 128)
      A1 = *(const half8*)(P + pb + (size_t)4 * PS * PS * CIN);
    const float* wb =
        W + ((size_t)wtap * CIN + kof0 + k0B) * COUT + n_base + nB;
#pragma unroll
    for (int j = 0; j < BJ; j++) BW[j] = wb[(size_t)j * COUT];
  };

  load_it(0, rA0, rA1, rB);

  for (int it = 0; it < NIT; ++it) {
    *(half8*)&As[sp][skq * 8] = rA0;
    if (M == 128) *(half8*)&As[sp + 64][skq * 8] = rA1;
    if (BJ == 8) {
      half8 hb;
#pragma unroll
      for (int j = 0; j < 8; j++) hb[j] = (_Float16)rB[j];
      *(half8*)&Bs[nB][k0B] = hb;
    } else {
      half4v hb;
#pragma unroll
      for (int j = 0; j < 4; j++) hb[j] = (_Float16)rB[j];
      *(half4v*)&Bs[nB][k0B] = hb;
    }
    __syncthreads();
    if (it + 1 < NIT) load_it(it + 1, nA0, nA1, nBv);
    half8 a0 = *(const half8*)&As[m0w + fr][fq * 8];
    half8 a1 = *(const half8*)&As[m0w + 16 + fr][fq * 8];
#pragma unroll
    for (int s = 0; s < NSUB; s++) {
      half8 b = *(const half8*)&Bs[n0w + s * 16 + fr][fq * 8];
      acc[0][s] = __builtin_amdgcn_mfma_f32_16x16x32_f16(a0, b, acc[0][s], 0, 0, 0);
      acc[1][s] = __builtin_amdgcn_mfma_f32_16x16x32_f16(a1, b, acc[1][s], 0, 0, 0);
    }
    __syncthreads();
    rA0 = nA0;
    rA1 = nA1;
#pragma unroll
    for (int j = 0; j < BJ; j++) rB[j] = nBv[j];
  }

#pragma unroll
  for (int i = 0; i < 2; i++) {
#pragma unroll
    for (int r = 0; r < 4; r++) {
      const int m = m0w + i * 16 + fq * 4 + r;
      const int mz = m >> 4, my = (m >> 2) & 3, mx = m & 3;
      if (STORE_MODE == 2) {
        const int oz = 2 * (u0z + mz) + clz;
        const int oy = 2 * (u0y + my) + cly;
        const int ox = 2 * (u0x + mx) + clx;
        _Float16* o = (_Float16*)Optr +
            ((size_t)(((oz + 1) * (S + 2) + (oy + 1)) * (S + 2) + (ox + 1))) *
                COUT + n_base + n0w;
#pragma unroll
        for (int s = 0; s < NSUB; s++)
          o[s * 16 + fr] = (_Float16)fmaxf(acc[i][s][r], 0.f);
      } else {
        const size_t pos =
            ((size_t)((u0z + mz) * SOUTU + (u0y + my))) * SOUTU + (u0x + mx);
        float* o = (float*)Optr + ((size_t)jspl * U3 + pos) * COUT + n_base +
                   n0w;
#pragma unroll
        for (int s = 0; s < NSUB; s++) o[s * 16 + fr] = acc[i][s][r];
      }
    }
  }
}

// Layer 6: 32 -> 1 channels, per-output dot product from padded fp16 P6.
__global__ __launch_bounds__(256) void conv6_k(const _Float16* __restrict__ P,
                                               const float* __restrict__ W6,
                                               float* __restrict__ O) {
  __shared__ __align__(16) float w[864];  // 27*32
  for (int i = threadIdx.x; i < 864; i += 256) w[i] = W6[i];
  __syncthreads();
  int idx = blockIdx.x * 256 + threadIdx.x;  // 32768 outputs
  int x = idx & 31, y = (idx >> 5) & 31, z = idx >> 10;
  float a = 0.f;
  for (int dz = 0; dz < 3; dz++)
    for (int dy = 0; dy < 3; dy++)
      for (int dx = 0; dx < 3; dx++) {
        const _Float16* p =
            P + (size_t)(((z + dz) * 34 + (y + dy)) * 34 + (x + dx)) * 32;
        const float* ww = &w[((dz * 3 + dy) * 3 + dx) * 32];
#pragma unroll
        for (int c = 0; c < 32; c += 8) {
          half8 pv = *(const half8*)&p[c];
#pragma unroll
          for (int u = 0; u < 8; u++) a += (float)pv[u] * ww[c + u];
        }
      }
  O[idx] = a;
}

extern "C" void kernel_launch(void* const* d_in, const int* in_sizes, int n_in,
                              void* d_out, int out_size, void* d_ws,
                              size_t ws_size, hipStream_t stream) {
  const float* x  = (const float*)d_in[0];
  const float* w1 = (const float*)d_in[1];
  const float* w2 = (const float*)d_in[2];
  const float* w3 = (const float*)d_in[3];
  const float* w4 = (const float*)d_in[4];
  const float* w5 = (const float*)d_in[5];
  const float* w6 = (const float*)d_in[6];
  float* out = (float*)d_out;

  // fp32 partial slabs
  float* Q1 = (float*)d_ws;                  // 108 * 64   * 512 = 3538944
  float* Q2 = Q1 + 3538944;                  // 24  * 512  * 256 = 3145728
  float* Q3 = Q2 + 3145728;                  // 54  * 512  * 128 = 3538944
  float* Q4 = Q3 + 3538944;                  // 12  * 4096 * 64  = 3145728
  // fp16 padded activations
  _Float16* P1 = (_Float16*)(Q4 + 3145728);  // 5^3  * 1024 = 128000
  _Float16* P2 = P1 + 128000;                // 10^3 * 512  = 512000
  _Float16* P3 = P2 + 512000;                // 9^3  * 256  = 186624
  _Float16* P4 = P3 + 186624;                // 18^3 * 128  = 746496
  _Float16* P5 = P4 + 746496;                // 17^3 * 64   = 314432
  _Float16* P6 = P5 + 314432;                // 34^3 * 32   = 1257728

  // only P6 needs pre-zeroed borders (conv5 writes its interior directly)
  hipMemsetAsync(P6, 0, 1257728 * sizeof(_Float16), stream);

  // L1: 1024->512, 4^3 -> 8^3, s2; 27 pairs x 8 n x 4 ci = 864 blocks, NIT=8
  pad_x_k<<<500, 256, 0, stream>>>(x, P1);
  conv_mfma_k<256, 1024, 512, 64, 4, 4, 5, 1, 0, 3>
      <<<dim3(27, 8, 4), 256, 0, stream>>>(P1, w1, Q1);
  red_k<8, 512, 1, 4, 10><<<500, 256, 0, stream>>>(Q1, P2);
  // L2: 512->256, 8^3, s1; 3 tap-groups x 8 ci -> 24 splits, 384 blocks
  conv_mfma_k<64, 512, 256, 64, 8, 8, 10, 0, 9, 3>
      <<<dim3(4, 4, 24), 256, 0, stream>>>(P2, w2, Q2);
  red_k<8, 256, 0, 24, 9><<<183, 256, 0, stream>>>(Q2, P3);
  // L3: 256->128, 8^3 -> 16^3, s2; 27 pairs x 4 m x 2 n x 2 ci = 432 blocks
  conv_mfma_k<128, 256, 128, 64, 8, 8, 9, 1, 0, 3>
      <<<dim3(108, 2, 2), 256, 0, stream>>>(P3, w3, Q3);
  red_k<16, 128, 1, 2, 18><<<729, 256, 0, stream>>>(Q3, P4);
  // L4: 128->64, 16^3, s1; 3 tap-groups x 4 ci -> 12 splits, 384 blocks
  conv_mfma_k<32, 128, 64, 64, 8, 16, 18, 0, 9, 3>
      <<<dim3(32, 1, 12), 256, 0, stream>>>(P4, w4, Q4);
  red_k<16, 64, 0, 12, 17><<<308, 256, 0, stream>>>(Q4, P5);
  // L5: 64->32, 16^3 -> 32^3, s2 class-loop, fp16 ReLU store into padded P6
  conv_mfma_k<64, 64, 32, 32, 8, 16, 17, 2, 0, 2>
      <<<dim3(256, 1, 1), 256, 0, stream>>>(P5, w5, P6);
  // L6: 32->1, 32^3, s1, no final ReLU
  conv6_k<<<128, 256, 0, stream>>>(P6, w6, out);

  (void)in_sizes; (void)n_in; (void)out_size; (void)ws_size;
}